// Round 1
// baseline (2155.026 us; speedup 1.0000x reference)
//
#include <hip/hip_runtime.h>
#include <hip/hip_bf16.h>
#include <cstdint>

// Problem constants
#define BB 16
#define NN 4096
#define MM 1024
#define KNB 16
#define CIN 64
#define COUT 128
#define RTOT (BB*MM*KNB)   // 262144 rows

// ---------- helpers ----------
__device__ __forceinline__ float bflo(uint32_t u){ return __uint_as_float(u << 16); }
__device__ __forceinline__ float bfhi(uint32_t u){ return __uint_as_float(u & 0xffff0000u); }
__device__ __forceinline__ uint32_t f2bf_pk(float a, float b){
  uint32_t ua = __float_as_uint(a), ub = __float_as_uint(b);
  ua += 0x7fffu + ((ua >> 16) & 1u);   // RNE (values are finite, no NaN handling needed)
  ub += 0x7fffu + ((ub >> 16) & 1u);
  return (ua >> 16) | (ub & 0xffff0000u);
}

// ---------- K0a: transpose x1 [B,64,N] -> xt [B,N,64] ----------
__global__ __launch_bounds__(256) void k_transpose(const float* __restrict__ x1, float* __restrict__ xt){
  __shared__ float t[64][65];
  int b = blockIdx.x >> 6, nt = blockIdx.x & 63;
  int n0 = nt*64, tid = threadIdx.x;
  int c = tid>>2, q = tid&3;
  const float* src = x1 + ((size_t)(b*64 + c))*NN + n0 + q*16;
  #pragma unroll
  for (int j=0;j<4;j++){
    float4 f = *(const float4*)(src + j*4);
    t[c][q*16+j*4+0]=f.x; t[c][q*16+j*4+1]=f.y; t[c][q*16+j*4+2]=f.z; t[c][q*16+j*4+3]=f.w;
  }
  __syncthreads();
  int n = tid>>2, c0 = q*16;
  float* dst = xt + ((size_t)(b*NN + n0 + n))*64 + c0;
  #pragma unroll
  for (int j=0;j<4;j++){
    float4 o;
    o.x=t[c0+j*4+0][n]; o.y=t[c0+j*4+1][n]; o.z=t[c0+j*4+2][n]; o.w=t[c0+j*4+3][n];
    *(float4*)(dst + j*4) = o;
  }
}

// ---------- K0b: n1[i] = |p|^2 (np op order: (x*x + y*y) + z*z, plain ops) ----------
__global__ __launch_bounds__(256) void k_norms(const float* __restrict__ p1, float* __restrict__ n1){
  int i = blockIdx.x*256 + threadIdx.x;      // < B*N = 65536
  float x = p1[(size_t)i*3+0], y = p1[(size_t)i*3+1], z = p1[(size_t)i*3+2];
  n1[i] = __fadd_rn(__fadd_rn(__fmul_rn(x,x),__fmul_rn(y,y)),__fmul_rn(z,z));
}

// ---------- K1: farthest point sampling (exact np-order arithmetic) ----------
__global__ __launch_bounds__(512) void k_fps(const float* __restrict__ p1,
                                             float* __restrict__ outp2, float* __restrict__ p2w){
  __shared__ float pc[NN*3];
  __shared__ float redv[2][8];
  __shared__ int   redi[2][8];
  int b = blockIdx.x, tid = threadIdx.x;
  int lane = tid & 63, wid = tid >> 6;
  const float* pb = p1 + (size_t)b*NN*3;
  float4 f[6];
  const float4* src = (const float4*)(pb + tid*24);
  #pragma unroll
  for (int j=0;j<6;j++) f[j] = src[j];
  float4* lp = (float4*)(pc + tid*24);
  #pragma unroll
  for (int j=0;j<6;j++) lp[j] = f[j];
  const float* fa = (const float*)f;
  float px[8],py[8],pz[8],dist[8];
  #pragma unroll
  for (int j=0;j<8;j++){ px[j]=fa[3*j]; py[j]=fa[3*j+1]; pz[j]=fa[3*j+2]; dist[j]=1e10f; }
  __syncthreads();
  float cx = pc[0], cy = pc[1], cz = pc[2];
  if (tid==0){
    float* o = outp2 + (size_t)b*MM*3; o[0]=cx; o[1]=cy; o[2]=cz;
    float n2 = __fadd_rn(__fadd_rn(__fmul_rn(cx,cx),__fmul_rn(cy,cy)),__fmul_rn(cz,cz));
    float* qq = p2w + (size_t)b*MM*4; qq[0]=cx; qq[1]=cy; qq[2]=cz; qq[3]=n2;
  }
  int g0 = tid*8;
  for (int i=1;i<MM;i++){
    float mval = -1.0f; int midx = 0;
    #pragma unroll
    for (int j=0;j<8;j++){
      float dx=__fsub_rn(px[j],cx), dy=__fsub_rn(py[j],cy), dz=__fsub_rn(pz[j],cz);
      float d = __fadd_rn(__fadd_rn(__fmul_rn(dx,dx),__fmul_rn(dy,dy)),__fmul_rn(dz,dz));
      float nd = fminf(dist[j], d); dist[j] = nd;
      if (nd > mval){ mval = nd; midx = g0 + j; }
    }
    #pragma unroll
    for (int off=32; off>=1; off>>=1){
      float ov = __shfl_xor(mval, off); int oi = __shfl_xor(midx, off);
      if (ov > mval || (ov == mval && oi < midx)){ mval = ov; midx = oi; }
    }
    int pbuf = i & 1;
    if (lane==0){ redv[pbuf][wid] = mval; redi[pbuf][wid] = midx; }
    __syncthreads();
    float wv = redv[pbuf][0]; int wi = redi[pbuf][0];
    #pragma unroll
    for (int w=1;w<8;w++){
      float rv = redv[pbuf][w]; int ri = redi[pbuf][w];
      if (rv > wv || (rv == wv && ri < wi)){ wv = rv; wi = ri; }
    }
    cx = pc[wi*3+0]; cy = pc[wi*3+1]; cz = pc[wi*3+2];
    if (tid==0){
      float* o = outp2 + ((size_t)b*MM + i)*3; o[0]=cx; o[1]=cy; o[2]=cz;
      float n2 = __fadd_rn(__fadd_rn(__fmul_rn(cx,cx),__fmul_rn(cy,cy)),__fmul_rn(cz,cz));
      float* qq = p2w + ((size_t)b*MM + i)*4; qq[0]=cx; qq[1]=cy; qq[2]=cz; qq[3]=n2;
    }
    // no second barrier needed: redv/redi double-buffered by iteration parity
  }
}

// ---------- K2: kNN, one wave per query ----------
__global__ __launch_bounds__(256) void k_knn(const float* __restrict__ p1, const float* __restrict__ n1,
                                             const float* __restrict__ p2w, int* __restrict__ iknn){
  int tid = threadIdx.x, lane = tid & 63, w = tid >> 6;
  int q = blockIdx.x*4 + w;
  int b = q >> 10;
  const float4 qv = *(const float4*)(p2w + (size_t)q*4);   // x,y,z,|q|^2
  const float* pb = p1 + (size_t)b*NN*3;
  const float* nb = n1 + (size_t)b*NN;
  float bd[16]; int bi[16];
  #pragma unroll
  for (int s=0;s<16;s++){ bd[s] = 1e30f; bi[s] = 0; }
  float wv = 1e30f; int wslot = 0;
  for (int t=0;t<64;t++){
    int c = t*64 + lane;
    float x = pb[(size_t)c*3+0], y = pb[(size_t)c*3+1], z = pb[(size_t)c*3+2];
    float nn = nb[c];
    float dot = fmaf(qv.z, z, fmaf(qv.y, y, __fmul_rn(qv.x, x)));   // BLAS-style fma chain
    float d2 = __fsub_rn(__fadd_rn(qv.w, nn), __fmul_rn(2.0f, dot));
    if (d2 < wv){
      #pragma unroll
      for (int s=0;s<16;s++) if (s==wslot){ bd[s]=d2; bi[s]=c; }
      wv = bd[0]; wslot = 0;
      #pragma unroll
      for (int s=1;s<16;s++) if (bd[s] > wv){ wv = bd[s]; wslot = s; }
    }
  }
  float lv = bd[0]; int ls = 0;
  #pragma unroll
  for (int s=1;s<16;s++) if (bd[s] < lv){ lv = bd[s]; ls = s; }
  for (int r=0;r<16;r++){
    float rv = lv; int rl = lane;
    #pragma unroll
    for (int off=32; off>=1; off>>=1){
      float ov = __shfl_xor(rv, off); int ol = __shfl_xor(rl, off);
      if (ov < rv || (ov == rv && ol < rl)){ rv = ov; rl = ol; }
    }
    if (lane == rl){
      int idx = 0;
      #pragma unroll
      for (int s=0;s<16;s++) if (s==ls) idx = bi[s];
      iknn[(size_t)q*16 + r] = idx;
      #pragma unroll
      for (int s=0;s<16;s++) if (s==ls) bd[s] = 1e30f;
      lv = bd[0]; ls = 0;
      #pragma unroll
      for (int s=1;s<16;s++) if (bd[s] < lv){ lv = bd[s]; ls = s; }
    }
  }
}

// ---------- K4: GEMM1 (fused gather) + stats atomics, h1 out (bf16) ----------
__global__ __launch_bounds__(256) void k_gemm1(const float* __restrict__ xt, const int* __restrict__ iknn,
                                               const float* __restrict__ p1, const float* __restrict__ p2w,
                                               const float* __restrict__ w1,
                                               __hip_bfloat16* __restrict__ h1, float* __restrict__ stats){
  __shared__ float At[68*64];          // At[c][row], c in [0,67)
  __shared__ float Wt[67*128];         // Wt[c][o]
  __shared__ float ssum[128], ssq[128];
  int tid = threadIdx.x;
  int r0 = blockIdx.x * 64;
  int b = r0 >> 14;                    // 16384 rows per batch
  for (int e = tid; e < 8576; e += 256){
    int o = e / 67; int c = e - o*67;
    Wt[c*128 + o] = w1[e];
  }
  if (tid < 128){ ssum[tid] = 0.f; ssq[tid] = 0.f; }
  int row = tid >> 2, sub = tid & 3;
  {
    int r = r0 + row;
    int n = iknn[r];
    int mg = r >> 4;                   // global (b*M+m)
    const float* xr = xt + ((size_t)(b*NN + n))*64 + sub*16;
    #pragma unroll
    for (int j=0;j<4;j++){
      float4 v = *(const float4*)(xr + j*4);
      int cb = 3 + sub*16 + j*4;
      At[(cb+0)*64+row]=v.x; At[(cb+1)*64+row]=v.y; At[(cb+2)*64+row]=v.z; At[(cb+3)*64+row]=v.w;
    }
    if (sub==0){
      const float* pp = p1 + ((size_t)(b*NN + n))*3;
      const float* qq = p2w + (size_t)mg*4;
      At[0*64+row] = __fsub_rn(pp[0], qq[0]);
      At[1*64+row] = __fsub_rn(pp[1], qq[1]);
      At[2*64+row] = __fsub_rn(pp[2], qq[2]);
    }
  }
  __syncthreads();
  int tx = tid & 15, ty = tid >> 4;
  float acc[4][8];
  #pragma unroll
  for (int i=0;i<4;i++)
    #pragma unroll
    for (int j=0;j<8;j++) acc[i][j] = 0.f;
  for (int c=0;c<67;c++){
    float4 a  = *(const float4*)(At + c*64 + ty*4);
    float4 b0 = *(const float4*)(Wt + c*128 + tx*4);
    float4 b1 = *(const float4*)(Wt + c*128 + 64 + tx*4);
    float ar[4] = {a.x, a.y, a.z, a.w};
    #pragma unroll
    for (int i=0;i<4;i++){
      acc[i][0]=fmaf(ar[i],b0.x,acc[i][0]); acc[i][1]=fmaf(ar[i],b0.y,acc[i][1]);
      acc[i][2]=fmaf(ar[i],b0.z,acc[i][2]); acc[i][3]=fmaf(ar[i],b0.w,acc[i][3]);
      acc[i][4]=fmaf(ar[i],b1.x,acc[i][4]); acc[i][5]=fmaf(ar[i],b1.y,acc[i][5]);
      acc[i][6]=fmaf(ar[i],b1.z,acc[i][6]); acc[i][7]=fmaf(ar[i],b1.w,acc[i][7]);
    }
  }
  #pragma unroll
  for (int i=0;i<4;i++){
    size_t rr = (size_t)(r0 + ty*4 + i);
    uint2 u0, u1;
    u0.x = f2bf_pk(acc[i][0], acc[i][1]); u0.y = f2bf_pk(acc[i][2], acc[i][3]);
    u1.x = f2bf_pk(acc[i][4], acc[i][5]); u1.y = f2bf_pk(acc[i][6], acc[i][7]);
    *(uint2*)(h1 + rr*128 + tx*4)      = u0;
    *(uint2*)(h1 + rr*128 + 64 + tx*4) = u1;
  }
  #pragma unroll
  for (int j=0;j<8;j++){
    int col = (j<4) ? (tx*4+j) : (64 + tx*4 + (j-4));
    float s  = acc[0][j]+acc[1][j]+acc[2][j]+acc[3][j];
    float q2 = acc[0][j]*acc[0][j] + acc[1][j]*acc[1][j] + acc[2][j]*acc[2][j] + acc[3][j]*acc[3][j];
    atomicAdd(&ssum[col], s); atomicAdd(&ssq[col], q2);
  }
  __syncthreads();
  if (tid < 128){ atomicAdd(&stats[tid], ssum[tid]); atomicAdd(&stats[128+tid], ssq[tid]); }
}

// ---------- K5/K7: finalize BN scale/shift ----------
__global__ void k_fin(const float* __restrict__ g, const float* __restrict__ bbias,
                      float* __restrict__ stats, int io, int oo){
  int o = threadIdx.x;
  float inv = 1.0f / (float)RTOT;
  float mean = stats[io+o] * inv;
  float var  = stats[io+128+o] * inv - mean*mean;
  float rs = 1.0f / sqrtf(var + 1e-5f);
  float sc = g[o] * rs;
  stats[oo+o]     = sc;
  stats[oo+128+o] = bbias[o] - mean*sc;
}

// ---------- K6: GEMM2 (bn1+relu fused on load) + stats atomics, h2 out ----------
__global__ __launch_bounds__(256) void k_gemm2(const __hip_bfloat16* __restrict__ h1,
                                               const float* __restrict__ w2,
                                               const float* __restrict__ stats,
                                               __hip_bfloat16* __restrict__ h2){
  __shared__ float At[64*64];          // At[c][row], chunked K
  __shared__ float Wt[64*128];
  __shared__ float sc[128], sh[128], ssum[128], ssq[128];
  int tid = threadIdx.x;
  int r0 = blockIdx.x * 64;
  if (tid < 128){ sc[tid]=stats[512+tid]; sh[tid]=stats[640+tid]; ssum[tid]=0.f; ssq[tid]=0.f; }
  int row = tid >> 2, sub = tid & 3, tx = tid & 15, ty = tid >> 4;
  float acc[4][8];
  #pragma unroll
  for (int i=0;i<4;i++)
    #pragma unroll
    for (int j=0;j<8;j++) acc[i][j] = 0.f;
  for (int kc=0; kc<128; kc+=64){
    __syncthreads();
    {
      const uint2* hp = (const uint2*)(h1 + (size_t)(r0+row)*128 + kc + sub*16);
      #pragma unroll
      for (int j2=0;j2<4;j2++){
        uint2 u = hp[j2];
        int cl = sub*16 + j2*4, cg = kc + cl;
        float f0=bflo(u.x), f1=bfhi(u.x), f2=bflo(u.y), f3=bfhi(u.y);
        At[(cl+0)*64+row] = fmaxf(fmaf(f0, sc[cg+0], sh[cg+0]), 0.f);
        At[(cl+1)*64+row] = fmaxf(fmaf(f1, sc[cg+1], sh[cg+1]), 0.f);
        At[(cl+2)*64+row] = fmaxf(fmaf(f2, sc[cg+2], sh[cg+2]), 0.f);
        At[(cl+3)*64+row] = fmaxf(fmaf(f3, sc[cg+3], sh[cg+3]), 0.f);
      }
    }
    {
      int o = tid >> 1, ch = tid & 1;
      const float* wr = w2 + (size_t)o*128 + kc + ch*32;
      #pragma unroll
      for (int j=0;j<8;j++){
        float4 v = *(const float4*)(wr + j*4);
        int c = ch*32 + j*4;
        Wt[(c+0)*128+o]=v.x; Wt[(c+1)*128+o]=v.y; Wt[(c+2)*128+o]=v.z; Wt[(c+3)*128+o]=v.w;
      }
    }
    __syncthreads();
    for (int c=0;c<64;c++){
      float4 a  = *(const float4*)(At + c*64 + ty*4);
      float4 b0 = *(const float4*)(Wt + c*128 + tx*4);
      float4 b1 = *(const float4*)(Wt + c*128 + 64 + tx*4);
      float ar[4] = {a.x, a.y, a.z, a.w};
      #pragma unroll
      for (int i=0;i<4;i++){
        acc[i][0]=fmaf(ar[i],b0.x,acc[i][0]); acc[i][1]=fmaf(ar[i],b0.y,acc[i][1]);
        acc[i][2]=fmaf(ar[i],b0.z,acc[i][2]); acc[i][3]=fmaf(ar[i],b0.w,acc[i][3]);
        acc[i][4]=fmaf(ar[i],b1.x,acc[i][4]); acc[i][5]=fmaf(ar[i],b1.y,acc[i][5]);
        acc[i][6]=fmaf(ar[i],b1.z,acc[i][6]); acc[i][7]=fmaf(ar[i],b1.w,acc[i][7]);
      }
    }
  }
  float* statsBase = (float*)stats;    // const-cast for atomics (region is writable ws)
  #pragma unroll
  for (int i=0;i<4;i++){
    size_t rr = (size_t)(r0 + ty*4 + i);
    uint2 u0, u1;
    u0.x = f2bf_pk(acc[i][0], acc[i][1]); u0.y = f2bf_pk(acc[i][2], acc[i][3]);
    u1.x = f2bf_pk(acc[i][4], acc[i][5]); u1.y = f2bf_pk(acc[i][6], acc[i][7]);
    *(uint2*)(h2 + rr*128 + tx*4)      = u0;
    *(uint2*)(h2 + rr*128 + 64 + tx*4) = u1;
  }
  #pragma unroll
  for (int j=0;j<8;j++){
    int col = (j<4) ? (tx*4+j) : (64 + tx*4 + (j-4));
    float s  = acc[0][j]+acc[1][j]+acc[2][j]+acc[3][j];
    float q2 = acc[0][j]*acc[0][j] + acc[1][j]*acc[1][j] + acc[2][j]*acc[2][j] + acc[3][j]*acc[3][j];
    atomicAdd(&ssum[col], s); atomicAdd(&ssq[col], q2);
  }
  __syncthreads();
  if (tid < 128){ atomicAdd(&statsBase[256+tid], ssum[tid]); atomicAdd(&statsBase[384+tid], ssq[tid]); }
}

// ---------- K8: bn2+relu+maxpool over k, transposed coalesced write ----------
__global__ __launch_bounds__(256) void k_pool(const __hip_bfloat16* __restrict__ h2,
                                              const float* __restrict__ stats, float* __restrict__ out1){
  __shared__ float ot[128*65];
  __shared__ float scs[128], shs[128];
  int tid = threadIdx.x, blk = blockIdx.x;
  int b = blk >> 4, m0 = (blk & 15) * 64;
  if (tid < 128){ scs[tid]=stats[768+tid]; shs[tid]=stats[896+tid]; }
  __syncthreads();
  int ml = tid >> 2, oq = tid & 3, o0 = oq*32;
  float scr[32], shr[32], mx[32];
  #pragma unroll
  for (int j=0;j<32;j++){ scr[j]=scs[o0+j]; shr[j]=shs[o0+j]; mx[j]=0.f; }   // relu>=0 so 0-init ok
  size_t rbase = ((size_t)(b*MM + m0 + ml))*16;
  for (int k=0;k<16;k++){
    const uint2* hp = (const uint2*)(h2 + (rbase+k)*128 + o0);
    #pragma unroll
    for (int j2=0;j2<8;j2++){
      uint2 u = hp[j2]; int j = j2*4;
      float f0=bflo(u.x), f1=bfhi(u.x), f2=bflo(u.y), f3=bfhi(u.y);
      mx[j+0] = fmaxf(mx[j+0], fmaxf(fmaf(f0, scr[j+0], shr[j+0]), 0.f));
      mx[j+1] = fmaxf(mx[j+1], fmaxf(fmaf(f1, scr[j+1], shr[j+1]), 0.f));
      mx[j+2] = fmaxf(mx[j+2], fmaxf(fmaf(f2, scr[j+2], shr[j+2]), 0.f));
      mx[j+3] = fmaxf(mx[j+3], fmaxf(fmaf(f3, scr[j+3], shr[j+3]), 0.f));
    }
  }
  #pragma unroll
  for (int j=0;j<32;j++) ot[(o0+j)*65 + ml] = mx[j];
  __syncthreads();
  int o = tid >> 1, mh = tid & 1;
  float* dst = out1 + ((size_t)(b*COUT + o))*MM + m0 + mh*32;
  #pragma unroll
  for (int j2=0;j2<8;j2++){
    float4 v;
    v.x=ot[o*65+mh*32+j2*4+0]; v.y=ot[o*65+mh*32+j2*4+1];
    v.z=ot[o*65+mh*32+j2*4+2]; v.w=ot[o*65+mh*32+j2*4+3];
    *(float4*)(dst + j2*4) = v;
  }
}

extern "C" void kernel_launch(void* const* d_in, const int* in_sizes, int n_in,
                              void* d_out, int out_size, void* d_ws, size_t ws_size,
                              hipStream_t stream) {
  (void)in_sizes; (void)n_in; (void)out_size; (void)ws_size;
  const float* p1 = (const float*)d_in[0];
  const float* x1 = (const float*)d_in[1];
  const float* w1 = (const float*)d_in[2];
  const float* g1 = (const float*)d_in[3];
  const float* b1 = (const float*)d_in[4];
  const float* w2 = (const float*)d_in[5];
  const float* g2 = (const float*)d_in[6];
  const float* b2 = (const float*)d_in[7];
  float* out = (float*)d_out;
  float* ws  = (float*)d_ws;

  // ws layout (float indices); total ~152.6 MB
  float* xt    = ws;                                   // 4,194,304 f
  int*   iknn  = (int*)(ws + 4194304);                 //   262,144 i
  float* p2w   = ws + 4456448;                         //    65,536 f  [B,M,4] xyz+|q|^2
  float* n1    = ws + 4521984;                         //    65,536 f
  float* stats = ws + 4587520;                         //     1,024 f
  __hip_bfloat16* h1 = (__hip_bfloat16*)(ws + 4588544);    // 33,554,432 bf16
  __hip_bfloat16* h2 = (__hip_bfloat16*)(ws + 21365760);   // 33,554,432 bf16

  float* outp2 = out;            // [B,M,3]
  float* out1  = out + 49152;    // [B,128,M]

  hipMemsetAsync(stats, 0, 512*sizeof(float), stream);
  k_transpose<<<BB*64, 256, 0, stream>>>(x1, xt);
  k_norms<<<256, 256, 0, stream>>>(p1, n1);
  k_fps<<<BB, 512, 0, stream>>>(p1, outp2, p2w);
  k_knn<<<4096, 256, 0, stream>>>(p1, n1, p2w, iknn);
  k_gemm1<<<4096, 256, 0, stream>>>(xt, iknn, p1, p2w, w1, h1, stats);
  k_fin<<<1, 128, 0, stream>>>(g1, b1, stats, 0, 512);
  k_gemm2<<<4096, 256, 0, stream>>>(h1, w2, stats, h2);
  k_fin<<<1, 128, 0, stream>>>(g2, b2, stats, 256, 768);
  k_pool<<<256, 256, 0, stream>>>(h2, stats, out1);
}

// Round 2
// 1712.152 us; speedup vs baseline: 1.2587x; 1.2587x over previous
//
#include <hip/hip_runtime.h>
#include <hip/hip_bf16.h>
#include <cstdint>

// Problem constants
#define BB 16
#define NN 4096
#define MM 1024
#define KNB 16
#define CIN 64
#define COUT 128
#define RTOT (BB*MM*KNB)   // 262144 rows

// ---------- helpers ----------
__device__ __forceinline__ float bflo(uint32_t u){ return __uint_as_float(u << 16); }
__device__ __forceinline__ float bfhi(uint32_t u){ return __uint_as_float(u & 0xffff0000u); }
__device__ __forceinline__ uint32_t f2bf_pk(float a, float b){
  uint32_t ua = __float_as_uint(a), ub = __float_as_uint(b);
  ua += 0x7fffu + ((ua >> 16) & 1u);   // RNE (values are finite, no NaN handling needed)
  ub += 0x7fffu + ((ub >> 16) & 1u);
  return (ua >> 16) | (ub & 0xffff0000u);
}

// ---------- K0a: transpose x1 [B,64,N] -> xt [B,N,64] ----------
__global__ __launch_bounds__(256) void k_transpose(const float* __restrict__ x1, float* __restrict__ xt){
  __shared__ float t[64][65];
  int b = blockIdx.x >> 6, nt = blockIdx.x & 63;
  int n0 = nt*64, tid = threadIdx.x;
  int c = tid>>2, q = tid&3;
  const float* src = x1 + ((size_t)(b*64 + c))*NN + n0 + q*16;
  #pragma unroll
  for (int j=0;j<4;j++){
    float4 f = *(const float4*)(src + j*4);
    t[c][q*16+j*4+0]=f.x; t[c][q*16+j*4+1]=f.y; t[c][q*16+j*4+2]=f.z; t[c][q*16+j*4+3]=f.w;
  }
  __syncthreads();
  int n = tid>>2, c0 = q*16;
  float* dst = xt + ((size_t)(b*NN + n0 + n))*64 + c0;
  #pragma unroll
  for (int j=0;j<4;j++){
    float4 o;
    o.x=t[c0+j*4+0][n]; o.y=t[c0+j*4+1][n]; o.z=t[c0+j*4+2][n]; o.w=t[c0+j*4+3][n];
    *(float4*)(dst + j*4) = o;
  }
}

// ---------- K0b: n1[i] = |p|^2 (np op order: (x*x + y*y) + z*z, plain ops) ----------
__global__ __launch_bounds__(256) void k_norms(const float* __restrict__ p1, float* __restrict__ n1){
  int i = blockIdx.x*256 + threadIdx.x;      // < B*N = 65536
  float x = p1[(size_t)i*3+0], y = p1[(size_t)i*3+1], z = p1[(size_t)i*3+2];
  n1[i] = __fadd_rn(__fadd_rn(__fmul_rn(x,x),__fmul_rn(y,y)),__fmul_rn(z,z));
}

// ---------- K1: farthest point sampling v2 ----------
// Same selection semantics as v1 (exact np-order distance arithmetic, strict-> per-lane
// first-max, lowest-global-index tie-break in all reductions). Mechanics changed:
//  - no per-iteration global stores (sel[] in LDS, dumped at end) -> no vmcnt drain at barrier
//  - DPP (quad_perm xor1/xor2, row_ror:4/8) for row-16 argmax instead of ds-shuffles
//  - single barrier/iter: 32 row-winner candidates double-buffered in LDS; every wave
//    redundantly reduces all 32 (upper 32 lanes mirror lower via lane&31)
__global__ __launch_bounds__(512) void k_fps(const float* __restrict__ p1,
                                             float* __restrict__ outp2, float* __restrict__ p2w){
  __shared__ float pc[NN*3];          // 48 KB point coords
  __shared__ float4 sel[MM];          // 16 KB selected centroids
  __shared__ float2 cand[2][32];      // double-buffered row-16 winners
  int b = blockIdx.x, tid = threadIdx.x;
  int lane = tid & 63, wid = tid >> 6;
  const float* pb = p1 + (size_t)b*NN*3;
  float4 f[6];
  const float4* src = (const float4*)(pb + tid*24);
  #pragma unroll
  for (int j=0;j<6;j++) f[j] = src[j];
  float4* lp = (float4*)(pc + tid*24);
  #pragma unroll
  for (int j=0;j<6;j++) lp[j] = f[j];
  const float* fa = (const float*)f;
  float px[8],py[8],pz[8],dist[8];
  #pragma unroll
  for (int j=0;j<8;j++){ px[j]=fa[3*j]; py[j]=fa[3*j+1]; pz[j]=fa[3*j+2]; dist[j]=1e10f; }
  __syncthreads();
  float cx = pc[0], cy = pc[1], cz = pc[2];
  if (tid==0) sel[0] = make_float4(cx, cy, cz, 0.f);
  int g0 = tid*8;

  #define DPP_STEP(ctrl) { \
    int ov_i = __builtin_amdgcn_update_dpp(__float_as_int(mval), __float_as_int(mval), (ctrl), 0xf, 0xf, false); \
    int oi   = __builtin_amdgcn_update_dpp(midx, midx, (ctrl), 0xf, 0xf, false); \
    float ov = __int_as_float(ov_i); \
    if (ov > mval || (ov == mval && oi < midx)){ mval = ov; midx = oi; } }

  for (int i=1;i<MM;i++){
    float mval = -1.0f; int midx = 0;
    #pragma unroll
    for (int j=0;j<8;j++){
      float dx=__fsub_rn(px[j],cx), dy=__fsub_rn(py[j],cy), dz=__fsub_rn(pz[j],cz);
      float d = __fadd_rn(__fadd_rn(__fmul_rn(dx,dx),__fmul_rn(dy,dy)),__fmul_rn(dz,dz));
      float nd = fminf(dist[j], d); dist[j] = nd;
      if (nd > mval){ mval = nd; midx = g0 + j; }
    }
    // reduce within each row of 16 lanes (pure DPP, no LDS latency)
    DPP_STEP(0xB1);   // quad_perm xor1
    DPP_STEP(0x4E);   // quad_perm xor2
    DPP_STEP(0x124);  // row_ror:4
    DPP_STEP(0x128);  // row_ror:8
    int pbuf = i & 1;
    if ((lane & 15) == 0) cand[pbuf][wid*4 + (lane>>4)] = make_float2(mval, __int_as_float(midx));
    __syncthreads();
    // every wave reduces all 32 candidates (both 32-lane halves do identical work)
    float2 c = cand[pbuf][lane & 31];
    mval = c.x; midx = __float_as_int(c.y);
    DPP_STEP(0xB1);
    DPP_STEP(0x4E);
    DPP_STEP(0x124);
    DPP_STEP(0x128);
    {
      int ov_i = __builtin_amdgcn_ds_swizzle(__float_as_int(mval), 0x401F);  // xor16
      int oi   = __builtin_amdgcn_ds_swizzle(midx, 0x401F);
      float ov = __int_as_float(ov_i);
      if (ov > mval || (ov == mval && oi < midx)){ mval = ov; midx = oi; }
    }
    cx = pc[midx*3+0]; cy = pc[midx*3+1]; cz = pc[midx*3+2];
    if (tid==0) sel[i] = make_float4(cx, cy, cz, 0.f);
  }
  #undef DPP_STEP
  __syncthreads();
  for (int e = tid; e < MM; e += 512){
    float4 s = sel[e];
    float n2 = __fadd_rn(__fadd_rn(__fmul_rn(s.x,s.x),__fmul_rn(s.y,s.y)),__fmul_rn(s.z,s.z));
    float* o = outp2 + ((size_t)b*MM + e)*3;
    o[0]=s.x; o[1]=s.y; o[2]=s.z;
    *(float4*)(p2w + ((size_t)b*MM + e)*4) = make_float4(s.x, s.y, s.z, n2);
  }
}

// ---------- K2: kNN, one wave per query ----------
__global__ __launch_bounds__(256) void k_knn(const float* __restrict__ p1, const float* __restrict__ n1,
                                             const float* __restrict__ p2w, int* __restrict__ iknn){
  int tid = threadIdx.x, lane = tid & 63, w = tid >> 6;
  int q = blockIdx.x*4 + w;
  int b = q >> 10;
  const float4 qv = *(const float4*)(p2w + (size_t)q*4);   // x,y,z,|q|^2
  const float* pb = p1 + (size_t)b*NN*3;
  const float* nb = n1 + (size_t)b*NN;
  float bd[16]; int bi[16];
  #pragma unroll
  for (int s=0;s<16;s++){ bd[s] = 1e30f; bi[s] = 0; }
  float wv = 1e30f; int wslot = 0;
  for (int t=0;t<64;t++){
    int c = t*64 + lane;
    float x = pb[(size_t)c*3+0], y = pb[(size_t)c*3+1], z = pb[(size_t)c*3+2];
    float nn = nb[c];
    float dot = fmaf(qv.z, z, fmaf(qv.y, y, __fmul_rn(qv.x, x)));   // BLAS-style fma chain
    float d2 = __fsub_rn(__fadd_rn(qv.w, nn), __fmul_rn(2.0f, dot));
    if (d2 < wv){
      #pragma unroll
      for (int s=0;s<16;s++) if (s==wslot){ bd[s]=d2; bi[s]=c; }
      wv = bd[0]; wslot = 0;
      #pragma unroll
      for (int s=1;s<16;s++) if (bd[s] > wv){ wv = bd[s]; wslot = s; }
    }
  }
  float lv = bd[0]; int ls = 0;
  #pragma unroll
  for (int s=1;s<16;s++) if (bd[s] < lv){ lv = bd[s]; ls = s; }
  for (int r=0;r<16;r++){
    float rv = lv; int rl = lane;
    #pragma unroll
    for (int off=32; off>=1; off>>=1){
      float ov = __shfl_xor(rv, off); int ol = __shfl_xor(rl, off);
      if (ov < rv || (ov == rv && ol < rl)){ rv = ov; rl = ol; }
    }
    if (lane == rl){
      int idx = 0;
      #pragma unroll
      for (int s=0;s<16;s++) if (s==ls) idx = bi[s];
      iknn[(size_t)q*16 + r] = idx;
      #pragma unroll
      for (int s=0;s<16;s++) if (s==ls) bd[s] = 1e30f;
      lv = bd[0]; ls = 0;
      #pragma unroll
      for (int s=1;s<16;s++) if (bd[s] < lv){ lv = bd[s]; ls = s; }
    }
  }
}

// ---------- K4: GEMM1 (fused gather) + stats atomics, h1 out (bf16) ----------
__global__ __launch_bounds__(256) void k_gemm1(const float* __restrict__ xt, const int* __restrict__ iknn,
                                               const float* __restrict__ p1, const float* __restrict__ p2w,
                                               const float* __restrict__ w1,
                                               __hip_bfloat16* __restrict__ h1, float* __restrict__ stats){
  __shared__ float At[68*64];          // At[c][row], c in [0,67)
  __shared__ float Wt[67*128];         // Wt[c][o]
  __shared__ float ssum[128], ssq[128];
  int tid = threadIdx.x;
  int r0 = blockIdx.x * 64;
  int b = r0 >> 14;                    // 16384 rows per batch
  for (int e = tid; e < 8576; e += 256){
    int o = e / 67; int c = e - o*67;
    Wt[c*128 + o] = w1[e];
  }
  if (tid < 128){ ssum[tid] = 0.f; ssq[tid] = 0.f; }
  int row = tid >> 2, sub = tid & 3;
  {
    int r = r0 + row;
    int n = iknn[r];
    int mg = r >> 4;                   // global (b*M+m)
    const float* xr = xt + ((size_t)(b*NN + n))*64 + sub*16;
    #pragma unroll
    for (int j=0;j<4;j++){
      float4 v = *(const float4*)(xr + j*4);
      int cb = 3 + sub*16 + j*4;
      At[(cb+0)*64+row]=v.x; At[(cb+1)*64+row]=v.y; At[(cb+2)*64+row]=v.z; At[(cb+3)*64+row]=v.w;
    }
    if (sub==0){
      const float* pp = p1 + ((size_t)(b*NN + n))*3;
      const float* qq = p2w + (size_t)mg*4;
      At[0*64+row] = __fsub_rn(pp[0], qq[0]);
      At[1*64+row] = __fsub_rn(pp[1], qq[1]);
      At[2*64+row] = __fsub_rn(pp[2], qq[2]);
    }
  }
  __syncthreads();
  int tx = tid & 15, ty = tid >> 4;
  float acc[4][8];
  #pragma unroll
  for (int i=0;i<4;i++)
    #pragma unroll
    for (int j=0;j<8;j++) acc[i][j] = 0.f;
  for (int c=0;c<67;c++){
    float4 a  = *(const float4*)(At + c*64 + ty*4);
    float4 b0 = *(const float4*)(Wt + c*128 + tx*4);
    float4 b1 = *(const float4*)(Wt + c*128 + 64 + tx*4);
    float ar[4] = {a.x, a.y, a.z, a.w};
    #pragma unroll
    for (int i=0;i<4;i++){
      acc[i][0]=fmaf(ar[i],b0.x,acc[i][0]); acc[i][1]=fmaf(ar[i],b0.y,acc[i][1]);
      acc[i][2]=fmaf(ar[i],b0.z,acc[i][2]); acc[i][3]=fmaf(ar[i],b0.w,acc[i][3]);
      acc[i][4]=fmaf(ar[i],b1.x,acc[i][4]); acc[i][5]=fmaf(ar[i],b1.y,acc[i][5]);
      acc[i][6]=fmaf(ar[i],b1.z,acc[i][6]); acc[i][7]=fmaf(ar[i],b1.w,acc[i][7]);
    }
  }
  #pragma unroll
  for (int i=0;i<4;i++){
    size_t rr = (size_t)(r0 + ty*4 + i);
    uint2 u0, u1;
    u0.x = f2bf_pk(acc[i][0], acc[i][1]); u0.y = f2bf_pk(acc[i][2], acc[i][3]);
    u1.x = f2bf_pk(acc[i][4], acc[i][5]); u1.y = f2bf_pk(acc[i][6], acc[i][7]);
    *(uint2*)(h1 + rr*128 + tx*4)      = u0;
    *(uint2*)(h1 + rr*128 + 64 + tx*4) = u1;
  }
  #pragma unroll
  for (int j=0;j<8;j++){
    int col = (j<4) ? (tx*4+j) : (64 + tx*4 + (j-4));
    float s  = acc[0][j]+acc[1][j]+acc[2][j]+acc[3][j];
    float q2 = acc[0][j]*acc[0][j] + acc[1][j]*acc[1][j] + acc[2][j]*acc[2][j] + acc[3][j]*acc[3][j];
    atomicAdd(&ssum[col], s); atomicAdd(&ssq[col], q2);
  }
  __syncthreads();
  if (tid < 128){ atomicAdd(&stats[tid], ssum[tid]); atomicAdd(&stats[128+tid], ssq[tid]); }
}

// ---------- K5/K7: finalize BN scale/shift ----------
__global__ void k_fin(const float* __restrict__ g, const float* __restrict__ bbias,
                      float* __restrict__ stats, int io, int oo){
  int o = threadIdx.x;
  float inv = 1.0f / (float)RTOT;
  float mean = stats[io+o] * inv;
  float var  = stats[io+128+o] * inv - mean*mean;
  float rs = 1.0f / sqrtf(var + 1e-5f);
  float sc = g[o] * rs;
  stats[oo+o]     = sc;
  stats[oo+128+o] = bbias[o] - mean*sc;
}

// ---------- K6: GEMM2 (bn1+relu fused on load) + stats atomics, h2 out ----------
__global__ __launch_bounds__(256) void k_gemm2(const __hip_bfloat16* __restrict__ h1,
                                               const float* __restrict__ w2,
                                               const float* __restrict__ stats,
                                               __hip_bfloat16* __restrict__ h2){
  __shared__ float At[64*64];          // At[c][row], chunked K
  __shared__ float Wt[64*128];
  __shared__ float sc[128], sh[128], ssum[128], ssq[128];
  int tid = threadIdx.x;
  int r0 = blockIdx.x * 64;
  if (tid < 128){ sc[tid]=stats[512+tid]; sh[tid]=stats[640+tid]; ssum[tid]=0.f; ssq[tid]=0.f; }
  int row = tid >> 2, sub = tid & 3, tx = tid & 15, ty = tid >> 4;
  float acc[4][8];
  #pragma unroll
  for (int i=0;i<4;i++)
    #pragma unroll
    for (int j=0;j<8;j++) acc[i][j] = 0.f;
  for (int kc=0; kc<128; kc+=64){
    __syncthreads();
    {
      const uint2* hp = (const uint2*)(h1 + (size_t)(r0+row)*128 + kc + sub*16);
      #pragma unroll
      for (int j2=0;j2<4;j2++){
        uint2 u = hp[j2];
        int cl = sub*16 + j2*4, cg = kc + cl;
        float f0=bflo(u.x), f1=bfhi(u.x), f2=bflo(u.y), f3=bfhi(u.y);
        At[(cl+0)*64+row] = fmaxf(fmaf(f0, sc[cg+0], sh[cg+0]), 0.f);
        At[(cl+1)*64+row] = fmaxf(fmaf(f1, sc[cg+1], sh[cg+1]), 0.f);
        At[(cl+2)*64+row] = fmaxf(fmaf(f2, sc[cg+2], sh[cg+2]), 0.f);
        At[(cl+3)*64+row] = fmaxf(fmaf(f3, sc[cg+3], sh[cg+3]), 0.f);
      }
    }
    {
      int o = tid >> 1, ch = tid & 1;
      const float* wr = w2 + (size_t)o*128 + kc + ch*32;
      #pragma unroll
      for (int j=0;j<8;j++){
        float4 v = *(const float4*)(wr + j*4);
        int c = ch*32 + j*4;
        Wt[(c+0)*128+o]=v.x; Wt[(c+1)*128+o]=v.y; Wt[(c+2)*128+o]=v.z; Wt[(c+3)*128+o]=v.w;
      }
    }
    __syncthreads();
    for (int c=0;c<64;c++){
      float4 a  = *(const float4*)(At + c*64 + ty*4);
      float4 b0 = *(const float4*)(Wt + c*128 + tx*4);
      float4 b1 = *(const float4*)(Wt + c*128 + 64 + tx*4);
      float ar[4] = {a.x, a.y, a.z, a.w};
      #pragma unroll
      for (int i=0;i<4;i++){
        acc[i][0]=fmaf(ar[i],b0.x,acc[i][0]); acc[i][1]=fmaf(ar[i],b0.y,acc[i][1]);
        acc[i][2]=fmaf(ar[i],b0.z,acc[i][2]); acc[i][3]=fmaf(ar[i],b0.w,acc[i][3]);
        acc[i][4]=fmaf(ar[i],b1.x,acc[i][4]); acc[i][5]=fmaf(ar[i],b1.y,acc[i][5]);
        acc[i][6]=fmaf(ar[i],b1.z,acc[i][6]); acc[i][7]=fmaf(ar[i],b1.w,acc[i][7]);
      }
    }
  }
  float* statsBase = (float*)stats;    // const-cast for atomics (region is writable ws)
  #pragma unroll
  for (int i=0;i<4;i++){
    size_t rr = (size_t)(r0 + ty*4 + i);
    uint2 u0, u1;
    u0.x = f2bf_pk(acc[i][0], acc[i][1]); u0.y = f2bf_pk(acc[i][2], acc[i][3]);
    u1.x = f2bf_pk(acc[i][4], acc[i][5]); u1.y = f2bf_pk(acc[i][6], acc[i][7]);
    *(uint2*)(h2 + rr*128 + tx*4)      = u0;
    *(uint2*)(h2 + rr*128 + 64 + tx*4) = u1;
  }
  #pragma unroll
  for (int j=0;j<8;j++){
    int col = (j<4) ? (tx*4+j) : (64 + tx*4 + (j-4));
    float s  = acc[0][j]+acc[1][j]+acc[2][j]+acc[3][j];
    float q2 = acc[0][j]*acc[0][j] + acc[1][j]*acc[1][j] + acc[2][j]*acc[2][j] + acc[3][j]*acc[3][j];
    atomicAdd(&ssum[col], s); atomicAdd(&ssq[col], q2);
  }
  __syncthreads();
  if (tid < 128){ atomicAdd(&statsBase[256+tid], ssum[tid]); atomicAdd(&statsBase[384+tid], ssq[tid]); }
}

// ---------- K8: bn2+relu+maxpool over k, transposed coalesced write ----------
__global__ __launch_bounds__(256) void k_pool(const __hip_bfloat16* __restrict__ h2,
                                              const float* __restrict__ stats, float* __restrict__ out1){
  __shared__ float ot[128*65];
  __shared__ float scs[128], shs[128];
  int tid = threadIdx.x, blk = blockIdx.x;
  int b = blk >> 4, m0 = (blk & 15) * 64;
  if (tid < 128){ scs[tid]=stats[768+tid]; shs[tid]=stats[896+tid]; }
  __syncthreads();
  int ml = tid >> 2, oq = tid & 3, o0 = oq*32;
  float scr[32], shr[32], mx[32];
  #pragma unroll
  for (int j=0;j<32;j++){ scr[j]=scs[o0+j]; shr[j]=shs[o0+j]; mx[j]=0.f; }   // relu>=0 so 0-init ok
  size_t rbase = ((size_t)(b*MM + m0 + ml))*16;
  for (int k=0;k<16;k++){
    const uint2* hp = (const uint2*)(h2 + (rbase+k)*128 + o0);
    #pragma unroll
    for (int j2=0;j2<8;j2++){
      uint2 u = hp[j2]; int j = j2*4;
      float f0=bflo(u.x), f1=bfhi(u.x), f2=bflo(u.y), f3=bfhi(u.y);
      mx[j+0] = fmaxf(mx[j+0], fmaxf(fmaf(f0, scr[j+0], shr[j+0]), 0.f));
      mx[j+1] = fmaxf(mx[j+1], fmaxf(fmaf(f1, scr[j+1], shr[j+1]), 0.f));
      mx[j+2] = fmaxf(mx[j+2], fmaxf(fmaf(f2, scr[j+2], shr[j+2]), 0.f));
      mx[j+3] = fmaxf(mx[j+3], fmaxf(fmaf(f3, scr[j+3], shr[j+3]), 0.f));
    }
  }
  #pragma unroll
  for (int j=0;j<32;j++) ot[(o0+j)*65 + ml] = mx[j];
  __syncthreads();
  int o = tid >> 1, mh = tid & 1;
  float* dst = out1 + ((size_t)(b*COUT + o))*MM + m0 + mh*32;
  #pragma unroll
  for (int j2=0;j2<8;j2++){
    float4 v;
    v.x=ot[o*65+mh*32+j2*4+0]; v.y=ot[o*65+mh*32+j2*4+1];
    v.z=ot[o*65+mh*32+j2*4+2]; v.w=ot[o*65+mh*32+j2*4+3];
    *(float4*)(dst + j2*4) = v;
  }
}

extern "C" void kernel_launch(void* const* d_in, const int* in_sizes, int n_in,
                              void* d_out, int out_size, void* d_ws, size_t ws_size,
                              hipStream_t stream) {
  (void)in_sizes; (void)n_in; (void)out_size; (void)ws_size;
  const float* p1 = (const float*)d_in[0];
  const float* x1 = (const float*)d_in[1];
  const float* w1 = (const float*)d_in[2];
  const float* g1 = (const float*)d_in[3];
  const float* b1 = (const float*)d_in[4];
  const float* w2 = (const float*)d_in[5];
  const float* g2 = (const float*)d_in[6];
  const float* b2 = (const float*)d_in[7];
  float* out = (float*)d_out;
  float* ws  = (float*)d_ws;

  // ws layout (float indices); total ~152.6 MB
  float* xt    = ws;                                   // 4,194,304 f
  int*   iknn  = (int*)(ws + 4194304);                 //   262,144 i
  float* p2w   = ws + 4456448;                         //    65,536 f  [B,M,4] xyz+|q|^2
  float* n1    = ws + 4521984;                         //    65,536 f
  float* stats = ws + 4587520;                         //     1,024 f
  __hip_bfloat16* h1 = (__hip_bfloat16*)(ws + 4588544);    // 33,554,432 bf16
  __hip_bfloat16* h2 = (__hip_bfloat16*)(ws + 21365760);   // 33,554,432 bf16

  float* outp2 = out;            // [B,M,3]
  float* out1  = out + 49152;    // [B,128,M]

  hipMemsetAsync(stats, 0, 512*sizeof(float), stream);
  k_transpose<<<BB*64, 256, 0, stream>>>(x1, xt);
  k_norms<<<256, 256, 0, stream>>>(p1, n1);
  k_fps<<<BB, 512, 0, stream>>>(p1, outp2, p2w);
  k_knn<<<4096, 256, 0, stream>>>(p1, n1, p2w, iknn);
  k_gemm1<<<4096, 256, 0, stream>>>(xt, iknn, p1, p2w, w1, h1, stats);
  k_fin<<<1, 128, 0, stream>>>(g1, b1, stats, 0, 512);
  k_gemm2<<<4096, 256, 0, stream>>>(h1, w2, stats, h2);
  k_fin<<<1, 128, 0, stream>>>(g2, b2, stats, 256, 768);
  k_pool<<<256, 256, 0, stream>>>(h2, stats, out1);
}